// Round 1
// baseline (9073.476 us; speedup 1.0000x reference)
//
#include <hip/hip_runtime.h>
#include <hip/hip_bf16.h>

typedef __bf16 bf16x8 __attribute__((ext_vector_type(8)));
typedef float f32x4 __attribute__((ext_vector_type(4)));
typedef __hip_bfloat16 bf16s;

constexpr int kB = 16, kT = 24, kN = 2048, kD = 64;
constexpr int kRows = kB * kN;                 // 32768 = B*N
constexpr size_t kBND = (size_t)kB * kN * kD;  // 2097152

__device__ __forceinline__ void async_copy16(void* lds, const void* g) {
  __builtin_amdgcn_global_load_lds((const __attribute__((address_space(1))) void*)g,
                                   (__attribute__((address_space(3))) void*)lds,
                                   16, 0, 0);
}

// ---------------- core MFMA GEMM tile: BM=128, BK=64, BN in {128,64} ----------------
// A: row-major [M, K] with leading-dim lda (K-contiguous)
// B: "BT" layout rows = output column c, elements K-contiguous.
//    physical row address = ((c>>6)*bstr + trow + (c&63)) * ldb   (handles [B,D,N] slabs;
//    for plain row-major pass bstr=64, trow=0)
template<int BN>
__device__ __forceinline__ void gemm_core(
    const bf16s* A, int lda, int m0,
    const bf16s* Bop, int ldb, int bstr, int trow, int n0,
    int K, bf16s* lA, bf16s* lB, f32x4 (&acc)[4][BN / 32])
{
  constexpr int FN = BN / 32;
  const int tid = threadIdx.x;
  const int lane = tid & 63;
  const int wave = tid >> 6;
  const int wm = (wave >> 1) * 64;
  const int wn = (wave & 1) * (BN / 2);

  const f32x4 zero = {0.f, 0.f, 0.f, 0.f};
#pragma unroll
  for (int i = 0; i < 4; ++i)
#pragma unroll
    for (int j = 0; j < FN; ++j) acc[i][j] = zero;

  const int ra = tid >> 3;        // 0..31 : row within issue-group
  const int kc = (tid & 7) * 8;   // element offset of 16B chunk within a 64-elem K-row

  for (int k0 = 0; k0 < K; k0 += 64) {
    // stage A-tile [128][64] bf16 = 16KB, 4 issues x 256 lanes x 16B
#pragma unroll
    for (int i = 0; i < 4; ++i) {
      int row = i * 32 + ra;
      async_copy16(lA + (size_t)(i * 256 + tid) * 8,
                   A + (size_t)(m0 + row) * lda + k0 + kc);
    }
    // stage B-tile [BN][64]
#pragma unroll
    for (int i = 0; i < FN; ++i) {
      int c = n0 + i * 32 + ra;
      size_t gr = ((size_t)(c >> 6) * bstr + trow + (c & 63)) * (size_t)ldb;
      async_copy16(lB + (size_t)(i * 256 + tid) * 8, Bop + gr + k0 + kc);
    }
    __syncthreads();
#pragma unroll
    for (int ks = 0; ks < 2; ++ks) {
      bf16x8 av[4], bv[FN];
#pragma unroll
      for (int f = 0; f < 4; ++f)
        av[f] = *(const bf16x8*)(lA + (size_t)(wm + f * 16 + (lane & 15)) * 64 + ks * 32 + (lane >> 4) * 8);
#pragma unroll
      for (int f = 0; f < FN; ++f)
        bv[f] = *(const bf16x8*)(lB + (size_t)(wn + f * 16 + (lane & 15)) * 64 + ks * 32 + (lane >> 4) * 8);
#pragma unroll
      for (int i = 0; i < 4; ++i)
#pragma unroll
        for (int j = 0; j < FN; ++j)
          acc[i][j] = __builtin_amdgcn_mfma_f32_16x16x32_bf16(av[i], bv[j], acc[i][j], 0, 0, 0);
    }
    __syncthreads();
  }
}

// ---------------- diffusion: concat[:, slot*64 + d] = S @ X  (bf16 out) ----------------
// phase 0: z in {0..3}: (A,x)->slot2 (A,h)->slot3 (A2,x)->slot4 (A2,h)->slot5
// phase 1: z in {0,1}:  (A,zh)->slot3 (A2,zh)->slot5
__global__ __launch_bounds__(256) void k_diff(
    const bf16s* S0, const bf16s* S1,
    const bf16s* BX, int bxStr, int bxTrow,
    const bf16s* BH, bf16s* cc, int phase)
{
  __shared__ bf16s lA[128 * 64];
  __shared__ bf16s lB[128 * 64];
  const int z = blockIdx.z;
  const bf16s* S; const bf16s* Bop; int slot, bstr, trow;
  if (phase == 0) {
    S = (z >> 1) ? S1 : S0;
    if (z & 1) { Bop = BH; bstr = 64; trow = 0; }
    else       { Bop = BX; bstr = bxStr; trow = bxTrow; }
    slot = 2 + z;
  } else {
    S = z ? S1 : S0;
    Bop = BH; bstr = 64; trow = 0;
    slot = 3 + 2 * z;
  }
  const int m0 = blockIdx.x * 128;   // node n
  const int n0 = blockIdx.y * 128;   // c = b*64+d
  f32x4 acc[4][4];
  gemm_core<128>(S, 2048, m0, Bop, 2048, bstr, trow, n0, 2048, lA, lB, acc);

  const int lane = threadIdx.x & 63, wave = threadIdx.x >> 6;
  const int wm = (wave >> 1) * 64, wn = (wave & 1) * 64;
  const int rq = (lane >> 4) * 4, cl = lane & 15;
#pragma unroll
  for (int fm = 0; fm < 4; ++fm)
#pragma unroll
    for (int fn = 0; fn < 4; ++fn)
#pragma unroll
      for (int q = 0; q < 4; ++q) {
        int gm = m0 + wm + fm * 16 + rq + q;
        int gc = n0 + wn + fn * 16 + cl;
        size_t off = ((size_t)(gc >> 6) * 2048 + gm) * 384 + slot * 64 + (gc & 63);
        cc[off] = __float2bfloat16(acc[fm][fn][q]);
      }
}

// ---------------- setup GEMM: A2 = 2*A@A - I (bf16 out) ----------------
__global__ __launch_bounds__(256) void k_a2(const bf16s* Abf, const bf16s* ATbf, bf16s* A2)
{
  __shared__ bf16s lA[128 * 64];
  __shared__ bf16s lB[128 * 64];
  const int m0 = blockIdx.x * 128, n0 = blockIdx.y * 128;
  f32x4 acc[4][4];
  gemm_core<128>(Abf, 2048, m0, ATbf, 2048, 64, 0, n0, 2048, lA, lB, acc);
  const int lane = threadIdx.x & 63, wave = threadIdx.x >> 6;
  const int wm = (wave >> 1) * 64, wn = (wave & 1) * 64;
  const int rq = (lane >> 4) * 4, cl = lane & 15;
#pragma unroll
  for (int fm = 0; fm < 4; ++fm)
#pragma unroll
    for (int fn = 0; fn < 4; ++fn)
#pragma unroll
      for (int q = 0; q < 4; ++q) {
        int gm = m0 + wm + fm * 16 + rq + q;
        int gc = n0 + wn + fn * 16 + cl;
        A2[(size_t)gm * 2048 + gc] = __float2bfloat16(2.f * acc[fm][fn][q] - (gm == gc ? 1.f : 0.f));
      }
}

// ---------------- gate: zr = concat @ WgT^T + bg ; sigmoid ; zh = z*h ----------------
__global__ __launch_bounds__(256) void k_gate(
    const bf16s* ccv, const bf16s* WT, const float* bg,
    const float* h32, bf16s* ccw, bf16s* zhT, float* r32)
{
  __shared__ bf16s lA[128 * 64];
  __shared__ bf16s lB[128 * 64];
  const int m0 = blockIdx.x * 128;
  f32x4 acc[4][4];
  gemm_core<128>(ccv, 384, m0, WT, 384, 64, 0, 0, 384, lA, lB, acc);
  const int lane = threadIdx.x & 63, wave = threadIdx.x >> 6;
  const int wm = (wave >> 1) * 64, wn = (wave & 1) * 64;
  const int rq = (lane >> 4) * 4, cl = lane & 15;
#pragma unroll
  for (int fm = 0; fm < 4; ++fm)
#pragma unroll
    for (int fn = 0; fn < 4; ++fn) {
      const int o = wn + fn * 16 + cl;
      const float bias = bg[o];
#pragma unroll
      for (int q = 0; q < 4; ++q) {
        size_t gm = (size_t)m0 + wm + fm * 16 + rq + q;
        float s = 1.f / (1.f + expf(-(acc[fm][fn][q] + bias)));
        if (o < 64) {                       // z half
          float zh = s * h32[gm * 64 + o];
          ccw[gm * 384 + 64 + o] = __float2bfloat16(zh);
          zhT[((size_t)((gm >> 11) * 64 + o)) * 2048 + (gm & 2047)] = __float2bfloat16(zh);
        } else {                            // r half
          r32[gm * 64 + (o - 64)] = s;
        }
      }
    }
}

// ---------------- candidate: hc = tanh(...); GRU update; residual & next-slot writes ----------------
__global__ __launch_bounds__(256) void k_cand(
    const bf16s* ccv, const bf16s* WT, const float* bu,
    const float* r32, float* h32, bf16s* hT, bf16s* ccw,
    const float* cur_in, const float* x0, float* cur_out, float* hid_out, int t)
{
  __shared__ bf16s lA[128 * 64];
  __shared__ bf16s lB[64 * 64];
  const int m0 = blockIdx.x * 128;
  f32x4 acc[4][2];
  gemm_core<64>(ccv, 384, m0, WT, 384, 64, 0, 0, 384, lA, lB, acc);
  const int lane = threadIdx.x & 63, wave = threadIdx.x >> 6;
  const int wm = (wave >> 1) * 64, wn = (wave & 1) * 32;
  const int rq = (lane >> 4) * 4, cl = lane & 15;
#pragma unroll
  for (int fm = 0; fm < 4; ++fm)
#pragma unroll
    for (int fn = 0; fn < 2; ++fn) {
      const int d = wn + fn * 16 + cl;
      const float bias = bu[d];
#pragma unroll
      for (int q = 0; q < 4; ++q) {
        size_t gm = (size_t)m0 + wm + fm * 16 + rq + q;
        float hc = tanhf(acc[fm][fn][q] + bias);
        float r = r32[gm * 64 + d];
        float h = h32[gm * 64 + d];
        float hn = r * h + (1.f - r) * hc;
        h32[gm * 64 + d] = hn;
        int b = (int)(gm >> 11), n = (int)(gm & 2047);
        hT[((size_t)(b * 64 + d)) * 2048 + n] = __float2bfloat16(hn);
        ccw[gm * 384 + 64 + d] = __float2bfloat16(hn);            // slot1 <- h_new for next cell
        size_t xi = ((size_t)(b * kT + t) * 2048 + n) * 64 + d;
        cur_out[xi] = x0[xi] + hn;                                 // current = x + seq
        if (t + 1 < kT) {
          size_t xi2 = ((size_t)(b * kT + t + 1) * 2048 + n) * 64 + d;
          ccw[gm * 384 + d] = __float2bfloat16(cur_in[xi2]);       // slot0 <- next x_t
        } else {
          hid_out[gm * 64 + d] = hn;                               // hiddens[l]
        }
      }
    }
}

// ---------------- small utility kernels ----------------
__global__ __launch_bounds__(256) void transpose_cvt(
    const float* in, bf16s* out, int nrows, int ncols,
    size_t in_ostride, size_t out_ostride)
{
  __shared__ float tile[64][65];
  const int r0 = blockIdx.x * 64, c0 = blockIdx.y * 64;
  in  += (size_t)blockIdx.z * in_ostride;
  out += (size_t)blockIdx.z * out_ostride;
  const int tx = threadIdx.x & 63, ty = threadIdx.x >> 6;
#pragma unroll
  for (int i = 0; i < 64; i += 4)
    tile[ty + i][tx] = in[(size_t)(r0 + ty + i) * ncols + c0 + tx];
  __syncthreads();
#pragma unroll
  for (int i = 0; i < 64; i += 4)
    out[(size_t)(c0 + ty + i) * nrows + r0 + tx] = __float2bfloat16(tile[tx][ty + i]);
}

__global__ __launch_bounds__(256) void k_cvt(const float* in, bf16s* out, int n)
{
  int i = blockIdx.x * 256 + threadIdx.x;
  if (i < n) out[i] = __float2bfloat16(in[i]);
}

// Wg [L][3][128][128] -> WgT [L][128][384] ; Wu [L][3][128][64] -> WuT [L][64][384]
// K-slot layout: slot = 2*k + (cin>=64), inner = cin&63
__global__ __launch_bounds__(256) void k_repack(
    const float* Wg, const float* Wu, bf16s* WgT, bf16s* WuT)
{
  int idx = blockIdx.x * 256 + threadIdx.x;
  if (idx < 2 * 3 * 128 * 128) {
    int o = idx & 127, cin = (idx >> 7) & 127, k = (idx >> 14) % 3, l = idx / 49152;
    WgT[((size_t)(l * 128 + o)) * 384 + (2 * k + (cin >> 6)) * 64 + (cin & 63)] =
        __float2bfloat16(Wg[idx]);
  }
  if (idx < 2 * 3 * 128 * 64) {
    int o = idx & 63, cin = (idx >> 6) & 127, k = (idx >> 13) % 3, l = idx / 24576;
    WuT[((size_t)(l * 64 + o)) * 384 + (2 * k + (cin >> 6)) * 64 + (cin & 63)] =
        __float2bfloat16(Wu[idx]);
  }
}

__global__ __launch_bounds__(256) void init_layer(
    const float* ist_l, const float* cur, float* h32, bf16s* hT, bf16s* cc)
{
  size_t idx = (size_t)blockIdx.x * 256 + threadIdx.x;
  if (idx >= kBND) return;
  int d = (int)(idx & 63);
  size_t row = idx >> 6;
  int n = (int)(row & 2047), b = (int)(row >> 11);
  float h = ist_l[idx];
  h32[idx] = h;
  hT[((size_t)(b * 64 + d)) * 2048 + n] = __float2bfloat16(h);
  cc[row * 384 + 64 + d] = __float2bfloat16(h);                            // slot1 <- h0
  cc[row * 384 + d] = __float2bfloat16(cur[((size_t)b * kT * 2048 + n) * 64 + d]); // slot0 <- x_0
}

// ---------------- host orchestration ----------------
extern "C" void kernel_launch(void* const* d_in, const int* in_sizes, int n_in,
                              void* d_out, int out_size, void* d_ws, size_t ws_size,
                              hipStream_t stream)
{
  (void)in_sizes; (void)n_in; (void)out_size;
  const float* x   = (const float*)d_in[0];
  const float* ist = (const float*)d_in[1];
  const float* adj = (const float*)d_in[2];
  const float* Wg  = (const float*)d_in[3];
  const float* bg  = (const float*)d_in[4];
  const float* Wu  = (const float*)d_in[5];
  const float* bu  = (const float*)d_in[6];
  float* outCur = (float*)d_out;                       // [B,T,N,D]
  float* outHid = outCur + (size_t)kB * kT * kN * kD;  // [L,B,N,D]

  char* p = (char*)d_ws;
  auto carve = [&](size_t bytes) { char* q = p; p += (bytes + 255) & ~(size_t)255; return q; };
  bf16s* A_bf  = (bf16s*)carve((size_t)2048 * 2048 * 2);
  bf16s* AT_bf = (bf16s*)carve((size_t)2048 * 2048 * 2);
  bf16s* A2_bf = (bf16s*)carve((size_t)2048 * 2048 * 2);
  bf16s* WgT   = (bf16s*)carve((size_t)2 * 128 * 384 * 2);
  bf16s* WuT   = (bf16s*)carve((size_t)2 * 64 * 384 * 2);
  bf16s* cc    = (bf16s*)carve((size_t)kRows * 384 * 2);
  float* h32   = (float*)carve(kBND * 4);
  float* r32   = (float*)carve(kBND * 4);
  bf16s* hT    = (bf16s*)carve(kBND * 2);
  bf16s* zhT   = (bf16s*)carve(kBND * 2);
  size_t fixedBytes = (size_t)(p - (char*)d_ws);
  size_t bigBytes = (size_t)kB * kT * kD * kN * 2;     // full [B,T,D,N] bf16
  bool bigX = ws_size >= fixedBytes + bigBytes;
  bf16s* xT = (bf16s*)carve(bigX ? bigBytes : kBND * 2);

  // ---- one-time setup ----
  k_cvt<<<dim3((2048 * 2048 + 255) / 256), 256, 0, stream>>>(adj, A_bf, 2048 * 2048);
  transpose_cvt<<<dim3(32, 32, 1), 256, 0, stream>>>(adj, AT_bf, 2048, 2048, 0, 0);
  k_a2<<<dim3(16, 16, 1), 256, 0, stream>>>(A_bf, AT_bf, A2_bf);
  k_repack<<<dim3(384), 256, 0, stream>>>(Wg, Wu, WgT, WuT);

  for (int l = 0; l < 2; ++l) {
    const float* cur = (l == 0) ? x : outCur;
    if (bigX)  // transpose-convert the whole layer input to [B,T,D,N] bf16
      transpose_cvt<<<dim3(32, 1, kB * kT), 256, 0, stream>>>(cur, xT, 2048, 64, 131072, 131072);
    init_layer<<<dim3((int)(kBND / 256)), 256, 0, stream>>>(ist + (size_t)l * kBND, cur, h32, hT, cc);

    for (int t = 0; t < kT; ++t) {
      if (!bigX)
        transpose_cvt<<<dim3(32, 1, kB), 256, 0, stream>>>(
            cur + (size_t)t * 131072, xT, 2048, 64, (size_t)kT * 131072, 131072);
      // diffusion of x_t and h by A and A2 -> slots 2..5
      k_diff<<<dim3(16, 8, 4), 256, 0, stream>>>(
          A_bf, A2_bf, xT, bigX ? kT * 64 : 64, bigX ? t * 64 : 0, hT, cc, 0);
      // gate GEMM + sigmoid + zh
      k_gate<<<dim3(256, 1, 1), 256, 0, stream>>>(
          cc, WgT + (size_t)l * 128 * 384, bg + l * 128, h32, cc, zhT, r32);
      // diffusion of zh -> slots 3,5
      k_diff<<<dim3(16, 8, 2), 256, 0, stream>>>(
          A_bf, A2_bf, nullptr, 0, 0, zhT, cc, 1);
      // candidate GEMM + tanh + GRU update + residual + next-cell slot writes
      k_cand<<<dim3(256, 1, 1), 256, 0, stream>>>(
          cc, WuT + (size_t)l * 64 * 384, bu + l * 64, r32, h32, hT, cc,
          cur, x, outCur, outHid + (size_t)l * kBND, t);
    }
  }
}

// Round 2
// 7403.261 us; speedup vs baseline: 1.2256x; 1.2256x over previous
//
#include <hip/hip_runtime.h>
#include <hip/hip_bf16.h>
#include <math.h>

typedef __bf16 bf16x8 __attribute__((ext_vector_type(8)));
typedef float f32x4 __attribute__((ext_vector_type(4)));
typedef __hip_bfloat16 bf16s;

constexpr int kB = 16, kT = 24, kN = 2048, kD = 64;
constexpr size_t kBND = (size_t)kB * kN * kD;  // 2097152

struct SlotDesc { const void* p0; const void* p1; int astr; int trow; int isF32; };
struct Slots6 { SlotDesc s[6]; };
struct Out4f { float* o0; float* o1; float* o2; float* o3; };
struct Out4b { bf16s* o0; bf16s* o1; bf16s* o2; bf16s* o3; };

__device__ __forceinline__ void async_copy16(void* lds, const void* g) {
  __builtin_amdgcn_global_load_lds((const __attribute__((address_space(1))) void*)g,
                                   (__attribute__((address_space(3))) void*)lds,
                                   16, 0, 0);
}

// =============== unified diffusion GEMM ===============
// out[slab][(c>>6)*2048 + n][c&63] = S_slab @ Bsrc, S stacked over blockIdx.x>>4 (A / A2).
// columns c < xcols come from BX (row addr ((c>>6)*cstr + ctrow + (c&63))*2048),
// columns c >= xcols from BH (row addr (c-xcols)*2048). split-K via blockIdx.z (kLen chunk).
// slab = (mi>>4)*2 + (c>=xcols).  fp32 partials (offset z*kBND) or bf16 direct per useBf16.
__global__ __launch_bounds__(256) void k_diff(
    const bf16s* __restrict__ S0, const bf16s* __restrict__ S1,
    const bf16s* __restrict__ BX, int cstr, int ctrow, int xcols,
    const bf16s* __restrict__ BH,
    Out4f of, Out4b ob, int kLen, int useBf16)
{
  __shared__ bf16s lA[128 * 64];
  __shared__ bf16s lB[128 * 64];
  const int mi = blockIdx.x;
  const bf16s* S = (mi >> 4) ? S1 : S0;
  const int m0 = (mi & 15) * 128;
  const int n0 = blockIdx.y * 128;
  const int kOff = blockIdx.z * kLen;
  const int tid = threadIdx.x, lane = tid & 63, wave = tid >> 6;
  const int wm = (wave >> 1) * 64, wn = (wave & 1) * 64;
  const bool cHigh = (n0 >= xcols);

  f32x4 acc[4][4];
  const f32x4 zero = {0.f, 0.f, 0.f, 0.f};
#pragma unroll
  for (int i = 0; i < 4; ++i)
#pragma unroll
    for (int j = 0; j < 4; ++j) acc[i][j] = zero;

  const int ra = tid >> 3, kc = (tid & 7) * 8;

  for (int k0 = kOff; k0 < kOff + kLen; k0 += 64) {
#pragma unroll
    for (int i = 0; i < 4; ++i)
      async_copy16(lA + (size_t)(i * 256 + tid) * 8,
                   S + (size_t)(m0 + i * 32 + ra) * 2048 + k0 + kc);
#pragma unroll
    for (int i = 0; i < 4; ++i) {
      int c = n0 + i * 32 + ra;
      const bf16s* src; size_t raddr;
      if (!cHigh) { src = BX; raddr = ((size_t)(c >> 6) * cstr + ctrow + (c & 63)) * 2048; }
      else        { src = BH; raddr = (size_t)(c - xcols) * 2048; }
      async_copy16(lB + (size_t)(i * 256 + tid) * 8, src + raddr + k0 + kc);
    }
    __syncthreads();
#pragma unroll
    for (int ks = 0; ks < 2; ++ks) {
      bf16x8 av[4], bv[4];
#pragma unroll
      for (int f = 0; f < 4; ++f)
        av[f] = *(const bf16x8*)(lA + (size_t)(wm + f * 16 + (lane & 15)) * 64 + ks * 32 + (lane >> 4) * 8);
#pragma unroll
      for (int f = 0; f < 4; ++f)
        bv[f] = *(const bf16x8*)(lB + (size_t)(wn + f * 16 + (lane & 15)) * 64 + ks * 32 + (lane >> 4) * 8);
#pragma unroll
      for (int i = 0; i < 4; ++i)
#pragma unroll
        for (int j = 0; j < 4; ++j)
          acc[i][j] = __builtin_amdgcn_mfma_f32_16x16x32_bf16(av[i], bv[j], acc[i][j], 0, 0, 0);
    }
    __syncthreads();
  }

  const int slab = (mi >> 4) * 2 + (cHigh ? 1 : 0);
  float* fo = slab == 0 ? of.o0 : slab == 1 ? of.o1 : slab == 2 ? of.o2 : of.o3;
  bf16s* bo = slab == 0 ? ob.o0 : slab == 1 ? ob.o1 : slab == 2 ? ob.o2 : ob.o3;
  if (!useBf16) fo += (size_t)blockIdx.z * kBND;
  const int rq = (lane >> 4) * 4, cl = lane & 15;
#pragma unroll
  for (int fm = 0; fm < 4; ++fm)
#pragma unroll
    for (int fn = 0; fn < 4; ++fn)
#pragma unroll
      for (int q = 0; q < 4; ++q) {
        int gm = m0 + wm + fm * 16 + rq + q;
        int gc = n0 + wn + fn * 16 + cl;
        int c2 = cHigh ? gc - xcols : gc;
        size_t off = ((size_t)(c2 >> 6) * 2048 + gm) * 64 + (c2 & 63);
        if (useBf16) bo[off] = __float2bfloat16(acc[fm][fn][q]);
        else         fo[off] = acc[fm][fn][q];
      }
}

// =============== small GEMM core (gate/cand): K = 6 slots of 64 ===============
// A rows gm: addr per slot = ((gm>>11)*astr + trow + (gm&2047))*64 + k.
// slot types: bf16 (global_load_lds) / fp32 [+optional second partial] (load+add+cvt+ds_write).
template<int BN>
__device__ __forceinline__ void small_core(
    const Slots6& sl, int m0, const bf16s* __restrict__ W,
    bf16s* lA, bf16s* lB, f32x4 (&acc)[4][BN / 32])
{
  const int tid = threadIdx.x, lane = tid & 63, wave = tid >> 6;
  const int wm = (wave >> 1) * 64, wn = (wave & 1) * (BN / 2);
  const f32x4 zero = {0.f, 0.f, 0.f, 0.f};
#pragma unroll
  for (int i = 0; i < 4; ++i)
#pragma unroll
    for (int j = 0; j < BN / 32; ++j) acc[i][j] = zero;

  const int ra = tid >> 3, kc = (tid & 7) * 8;

#pragma unroll
  for (int ks = 0; ks < 6; ++ks) {
    const SlotDesc sd = sl.s[ks];
    if (!sd.isF32) {
      const bf16s* base = (const bf16s*)sd.p0;
#pragma unroll
      for (int i = 0; i < 4; ++i) {
        int row = m0 + i * 32 + ra;
        size_t roff = ((size_t)(row >> 11) * sd.astr + sd.trow + (row & 2047)) * 64 + kc;
        async_copy16(lA + (size_t)(i * 256 + tid) * 8, base + roff);
      }
    } else {
#pragma unroll
      for (int i = 0; i < 4; ++i) {
        int row = m0 + i * 32 + ra;
        size_t roff = ((size_t)(row >> 11) * sd.astr + sd.trow + (row & 2047)) * 64 + kc;
        const float4* q0 = (const float4*)((const float*)sd.p0 + roff);
        float4 a = q0[0], b = q0[1];
        if (sd.p1) {
          const float4* q1 = (const float4*)((const float*)sd.p1 + roff);
          float4 c = q1[0], d = q1[1];
          a.x += c.x; a.y += c.y; a.z += c.z; a.w += c.w;
          b.x += d.x; b.y += d.y; b.z += d.z; b.w += d.w;
        }
        union { bf16x8 v; bf16s h[8]; } u;
        u.h[0] = __float2bfloat16(a.x); u.h[1] = __float2bfloat16(a.y);
        u.h[2] = __float2bfloat16(a.z); u.h[3] = __float2bfloat16(a.w);
        u.h[4] = __float2bfloat16(b.x); u.h[5] = __float2bfloat16(b.y);
        u.h[6] = __float2bfloat16(b.z); u.h[7] = __float2bfloat16(b.w);
        *(bf16x8*)(lA + (size_t)(i * 256 + tid) * 8) = u.v;
      }
    }
#pragma unroll
    for (int i = 0; i < BN / 32; ++i)
      async_copy16(lB + (size_t)(i * 256 + tid) * 8, W + (size_t)(i * 32 + ra) * 384 + ks * 64 + kc);
    __syncthreads();
#pragma unroll
    for (int kss = 0; kss < 2; ++kss) {
      bf16x8 av[4], bv[BN / 32];
#pragma unroll
      for (int f = 0; f < 4; ++f)
        av[f] = *(const bf16x8*)(lA + (size_t)(wm + f * 16 + (lane & 15)) * 64 + kss * 32 + (lane >> 4) * 8);
#pragma unroll
      for (int f = 0; f < BN / 32; ++f)
        bv[f] = *(const bf16x8*)(lB + (size_t)(wn + f * 16 + (lane & 15)) * 64 + kss * 32 + (lane >> 4) * 8);
#pragma unroll
      for (int i = 0; i < 4; ++i)
#pragma unroll
        for (int j = 0; j < BN / 32; ++j)
          acc[i][j] = __builtin_amdgcn_mfma_f32_16x16x32_bf16(av[i], bv[j], acc[i][j], 0, 0, 0);
    }
    __syncthreads();
  }
}

// gate: zr = sigmoid(concat @ Wg^T + bg); write zh (bf16 row + transposed), r (fp32)
__global__ __launch_bounds__(256) void k_gate(
    Slots6 sl, const bf16s* __restrict__ W, const float* __restrict__ bg,
    const float* __restrict__ h32, bf16s* zh_bf, bf16s* zhT, float* r32)
{
  __shared__ bf16s lA[128 * 64];
  __shared__ bf16s lB[128 * 64];
  const int m0 = blockIdx.x * 128;
  f32x4 acc[4][4];
  small_core<128>(sl, m0, W, lA, lB, acc);
  const int lane = threadIdx.x & 63, wave = threadIdx.x >> 6;
  const int wm = (wave >> 1) * 64, wn = (wave & 1) * 64;
  const int rq = (lane >> 4) * 4, cl = lane & 15;
#pragma unroll
  for (int fm = 0; fm < 4; ++fm)
#pragma unroll
    for (int fn = 0; fn < 4; ++fn) {
      const int o = wn + fn * 16 + cl;
      const float bias = bg[o];
#pragma unroll
      for (int q = 0; q < 4; ++q) {
        size_t gm = (size_t)m0 + wm + fm * 16 + rq + q;
        float s = 1.f / (1.f + expf(-(acc[fm][fn][q] + bias)));
        if (o < 64) {
          float zh = s * h32[gm * 64 + o];
          zh_bf[gm * 64 + o] = __float2bfloat16(zh);
          zhT[((size_t)((gm >> 11) * 64 + o)) * 2048 + (gm & 2047)] = __float2bfloat16(zh);
        } else {
          r32[gm * 64 + (o - 64)] = s;
        }
      }
    }
}

// cand: hc = tanh(concat @ Wu^T + bu); GRU update; residual write; hiddens at t=T-1
__global__ __launch_bounds__(256) void k_cand(
    Slots6 sl, const bf16s* __restrict__ W, const float* __restrict__ bu,
    const float* __restrict__ r32, float* h32, bf16s* hT, bf16s* h_bf,
    const float* __restrict__ x0, float* outCur, float* outHid, int t)
{
  __shared__ bf16s lA[128 * 64];
  __shared__ bf16s lB[64 * 64];
  const int m0 = blockIdx.x * 128;
  f32x4 acc[4][2];
  small_core<64>(sl, m0, W, lA, lB, acc);
  const int lane = threadIdx.x & 63, wave = threadIdx.x >> 6;
  const int wm = (wave >> 1) * 64, wn = (wave & 1) * 32;
  const int rq = (lane >> 4) * 4, cl = lane & 15;
#pragma unroll
  for (int fm = 0; fm < 4; ++fm)
#pragma unroll
    for (int fn = 0; fn < 2; ++fn) {
      const int d = wn + fn * 16 + cl;
      const float bias = bu[d];
#pragma unroll
      for (int q = 0; q < 4; ++q) {
        size_t gm = (size_t)m0 + wm + fm * 16 + rq + q;
        float hc = tanhf(acc[fm][fn][q] + bias);
        float r = r32[gm * 64 + d];
        float h = h32[gm * 64 + d];
        float hn = r * h + (1.f - r) * hc;
        h32[gm * 64 + d] = hn;
        int b = (int)(gm >> 11), n = (int)(gm & 2047);
        hT[((size_t)(b * 64 + d)) * 2048 + n] = __float2bfloat16(hn);
        h_bf[gm * 64 + d] = __float2bfloat16(hn);
        size_t xi = (((size_t)b * kT + t) * 2048 + n) * 64 + d;
        outCur[xi] = x0[xi] + hn;
        if (t == kT - 1) outHid[gm * 64 + d] = hn;
      }
    }
}

// =============== setup: A2 = 2*A@A - I ===============
__global__ __launch_bounds__(256) void k_a2(
    const bf16s* __restrict__ A, const bf16s* __restrict__ AT, bf16s* A2)
{
  __shared__ bf16s lA[128 * 64];
  __shared__ bf16s lB[128 * 64];
  const int m0 = blockIdx.x * 128, n0 = blockIdx.y * 128;
  const int tid = threadIdx.x, lane = tid & 63, wave = tid >> 6;
  const int wm = (wave >> 1) * 64, wn = (wave & 1) * 64;
  f32x4 acc[4][4];
  const f32x4 zero = {0.f, 0.f, 0.f, 0.f};
#pragma unroll
  for (int i = 0; i < 4; ++i)
#pragma unroll
    for (int j = 0; j < 4; ++j) acc[i][j] = zero;
  const int ra = tid >> 3, kc = (tid & 7) * 8;
  for (int k0 = 0; k0 < 2048; k0 += 64) {
#pragma unroll
    for (int i = 0; i < 4; ++i) {
      async_copy16(lA + (size_t)(i * 256 + tid) * 8, A + (size_t)(m0 + i * 32 + ra) * 2048 + k0 + kc);
      async_copy16(lB + (size_t)(i * 256 + tid) * 8, AT + (size_t)(n0 + i * 32 + ra) * 2048 + k0 + kc);
    }
    __syncthreads();
#pragma unroll
    for (int ks = 0; ks < 2; ++ks) {
      bf16x8 av[4], bv[4];
#pragma unroll
      for (int f = 0; f < 4; ++f) {
        av[f] = *(const bf16x8*)(lA + (size_t)(wm + f * 16 + (lane & 15)) * 64 + ks * 32 + (lane >> 4) * 8);
        bv[f] = *(const bf16x8*)(lB + (size_t)(wn + f * 16 + (lane & 15)) * 64 + ks * 32 + (lane >> 4) * 8);
      }
#pragma unroll
      for (int i = 0; i < 4; ++i)
#pragma unroll
        for (int j = 0; j < 4; ++j)
          acc[i][j] = __builtin_amdgcn_mfma_f32_16x16x32_bf16(av[i], bv[j], acc[i][j], 0, 0, 0);
    }
    __syncthreads();
  }
  const int rq = (lane >> 4) * 4, cl = lane & 15;
#pragma unroll
  for (int fm = 0; fm < 4; ++fm)
#pragma unroll
    for (int fn = 0; fn < 4; ++fn)
#pragma unroll
      for (int q = 0; q < 4; ++q) {
        int gm = m0 + wm + fm * 16 + rq + q;
        int gc = n0 + wn + fn * 16 + cl;
        A2[(size_t)gm * 2048 + gc] = __float2bfloat16(2.f * acc[fm][fn][q] - (gm == gc ? 1.f : 0.f));
      }
}

// =============== utility kernels ===============
__global__ __launch_bounds__(256) void transpose_cvt(
    const float* in, bf16s* out, int nrows, int ncols,
    size_t in_ostride, size_t out_ostride)
{
  __shared__ float tile[64][65];
  const int r0 = blockIdx.x * 64, c0 = blockIdx.y * 64;
  in  += (size_t)blockIdx.z * in_ostride;
  out += (size_t)blockIdx.z * out_ostride;
  const int tx = threadIdx.x & 63, ty = threadIdx.x >> 6;
#pragma unroll
  for (int i = 0; i < 64; i += 4)
    tile[ty + i][tx] = in[(size_t)(r0 + ty + i) * ncols + c0 + tx];
  __syncthreads();
#pragma unroll
  for (int i = 0; i < 64; i += 4)
    out[(size_t)(c0 + ty + i) * nrows + r0 + tx] = __float2bfloat16(tile[tx][ty + i]);
}

__global__ __launch_bounds__(256) void k_cvt(const float* in, bf16s* out, int n)
{
  int i = blockIdx.x * 256 + threadIdx.x;
  if (i < n) out[i] = __float2bfloat16(in[i]);
}

// Wg [L][3][128][128] -> WgT [L][128][384]; Wu [L][3][128][64] -> WuT [L][64][384]
// K-slot: slot = 2*k + (cin>=64), inner = cin&63
__global__ __launch_bounds__(256) void k_repack(
    const float* Wg, const float* Wu, bf16s* WgT, bf16s* WuT)
{
  int idx = blockIdx.x * 256 + threadIdx.x;
  if (idx < 2 * 3 * 128 * 128) {
    int o = idx & 127, cin = (idx >> 7) & 127, k = (idx >> 14) % 3, l = idx / 49152;
    WgT[((size_t)(l * 128 + o)) * 384 + (2 * k + (cin >> 6)) * 64 + (cin & 63)] =
        __float2bfloat16(Wg[idx]);
  }
  if (idx < 2 * 3 * 128 * 64) {
    int o = idx & 63, cin = (idx >> 6) & 127, k = (idx >> 13) % 3, l = idx / 24576;
    WuT[((size_t)(l * 64 + o)) * 384 + (2 * k + (cin >> 6)) * 64 + (cin & 63)] =
        __float2bfloat16(Wu[idx]);
  }
}

__global__ __launch_bounds__(256) void init_layer(
    const float* ist_l, float* h32, bf16s* hT, bf16s* h_bf)
{
  size_t idx = (size_t)blockIdx.x * 256 + threadIdx.x;
  if (idx >= kBND) return;
  int d = (int)(idx & 63);
  size_t row = idx >> 6;
  int n = (int)(row & 2047), b = (int)(row >> 11);
  float h = ist_l[idx];
  h32[idx] = h;
  hT[((size_t)(b * 64 + d)) * 2048 + n] = __float2bfloat16(h);
  h_bf[idx] = __float2bfloat16(h);
}

// =============== host orchestration ===============
extern "C" void kernel_launch(void* const* d_in, const int* in_sizes, int n_in,
                              void* d_out, int out_size, void* d_ws, size_t ws_size,
                              hipStream_t stream)
{
  (void)in_sizes; (void)n_in; (void)out_size;
  const float* x   = (const float*)d_in[0];
  const float* ist = (const float*)d_in[1];
  const float* adj = (const float*)d_in[2];
  const float* Wg  = (const float*)d_in[3];
  const float* bg  = (const float*)d_in[4];
  const float* Wu  = (const float*)d_in[5];
  const float* bu  = (const float*)d_in[6];
  float* outCur = (float*)d_out;                       // [B,T,N,D]
  float* outHid = outCur + (size_t)kB * kT * kN * kD;  // [L,B,N,D]

  char* p = (char*)d_ws;
  auto carve = [&](size_t bytes) { char* q = p; p += (bytes + 255) & ~(size_t)255; return q; };
  bf16s* A_bf  = (bf16s*)carve((size_t)2048 * 2048 * 2);
  bf16s* AT_bf = (bf16s*)carve((size_t)2048 * 2048 * 2);
  bf16s* A2_bf = (bf16s*)carve((size_t)2048 * 2048 * 2);
  bf16s* WgT   = (bf16s*)carve((size_t)2 * 128 * 384 * 2);
  bf16s* WuT   = (bf16s*)carve((size_t)2 * 64 * 384 * 2);
  float* h32   = (float*)carve(kBND * 4);
  float* r32   = (float*)carve(kBND * 4);
  bf16s* hT    = (bf16s*)carve(kBND * 2);
  bf16s* zhT   = (bf16s*)carve(kBND * 2);
  bf16s* h_bf  = (bf16s*)carve(kBND * 2);
  bf16s* zh_bf = (bf16s*)carve(kBND * 2);

  size_t used = (size_t)(p - (char*)d_ws);
  size_t rem = (ws_size > used) ? ws_size - used : 0;
  const size_t xTfullB = (size_t)kB * kT * kD * kN * 2;  // 96 MiB
  const size_t slack = 1 << 16;

  int path;
  if      (rem >= 4 * kBND * 4 + 3 * xTfullB + slack) path = 0;  // BIG
  else if (rem >= 8 * kBND * 4 + xTfullB + slack)     path = 1;  // MID
  else                                                 path = 2;  // TINY
  const int SK = (path == 2) ? 1 : 2;

  float *pAx = nullptr, *pAh = nullptr, *pA2x = nullptr, *pA2h = nullptr;
  bf16s *bAx = nullptr, *bAh = nullptr, *bA2x = nullptr, *bA2h = nullptr;
  bf16s *xT = nullptr, *Ax = nullptr, *A2x = nullptr;
  if (path == 0) {
    float* part = (float*)carve(4 * kBND * 4);
    pAh = part; pA2h = part + 2 * kBND;
    xT  = (bf16s*)carve(xTfullB);
    Ax  = (bf16s*)carve(xTfullB);
    A2x = (bf16s*)carve(xTfullB);
  } else if (path == 1) {
    float* part = (float*)carve(8 * kBND * 4);
    pAx = part; pAh = part + 2 * kBND; pA2x = part + 4 * kBND; pA2h = part + 6 * kBND;
    xT = (bf16s*)carve(xTfullB);
  } else {
    bAx  = (bf16s*)carve(kBND * 2); bAh  = (bf16s*)carve(kBND * 2);
    bA2x = (bf16s*)carve(kBND * 2); bA2h = (bf16s*)carve(kBND * 2);
    xT   = (bf16s*)carve(kBND * 2);  // per-timestep [B,D,N]
  }

  // ---- one-time setup ----
  k_cvt<<<dim3((2048 * 2048 + 255) / 256), 256, 0, stream>>>(adj, A_bf, 2048 * 2048);
  transpose_cvt<<<dim3(32, 32, 1), 256, 0, stream>>>(adj, AT_bf, 2048, 2048, 0, 0);
  k_a2<<<dim3(16, 16, 1), 256, 0, stream>>>(A_bf, AT_bf, A2_bf);
  k_repack<<<dim3(384), 256, 0, stream>>>(Wg, Wu, WgT, WuT);

  for (int l = 0; l < 2; ++l) {
    const float* cur = (l == 0) ? x : outCur;
    if (path <= 1)  // full-layer transpose: [B,T,N,D] f32 -> [B,T,D,N] bf16
      transpose_cvt<<<dim3(32, 1, kB * kT), 256, 0, stream>>>(cur, xT, 2048, 64, 131072, 131072);
    if (path == 0)  // batched x-diffusion: Ax/A2x for all t in one GEMM
      k_diff<<<dim3(32, 192, 1), 256, 0, stream>>>(
          A_bf, A2_bf, xT, 64, 0, 24576, nullptr,
          Out4f{}, Out4b{Ax, nullptr, A2x, nullptr}, 2048, 1);
    init_layer<<<dim3((int)(kBND / 256)), 256, 0, stream>>>(ist + (size_t)l * kBND, h32, hT, h_bf);

    for (int t = 0; t < kT; ++t) {
      if (path == 2)
        transpose_cvt<<<dim3(32, 1, kB), 256, 0, stream>>>(
            cur + (size_t)t * 131072, xT, 2048, 64, (size_t)kT * 131072, 131072);

      // ---- phase 0 diffusion ----
      if (path == 0)
        k_diff<<<dim3(32, 8, 2), 256, 0, stream>>>(
            A_bf, A2_bf, nullptr, 0, 0, 0, hT,
            Out4f{nullptr, pAh, nullptr, pA2h}, Out4b{}, 1024, 0);
      else if (path == 1)
        k_diff<<<dim3(32, 16, 2), 256, 0, stream>>>(
            A_bf, A2_bf, xT, kT * 64, t * 64, 1024, hT,
            Out4f{pAx, pAh, pA2x, pA2h}, Out4b{}, 1024, 0);
      else
        k_diff<<<dim3(32, 16, 1), 256, 0, stream>>>(
            A_bf, A2_bf, xT, 64, 0, 1024, hT,
            Out4f{}, Out4b{bAx, bAh, bA2x, bA2h}, 2048, 1);

      // ---- gate ----
      Slots6 gs;
      gs.s[0] = SlotDesc{cur, nullptr, kT * 2048, t * 2048, 1};
      gs.s[1] = SlotDesc{h_bf, nullptr, 2048, 0, 0};
      if (path == 0) {
        gs.s[2] = SlotDesc{Ax,  nullptr, kT * 2048, t * 2048, 0};
        gs.s[4] = SlotDesc{A2x, nullptr, kT * 2048, t * 2048, 0};
      } else if (path == 1) {
        gs.s[2] = SlotDesc{pAx,  pAx + kBND,  2048, 0, 1};
        gs.s[4] = SlotDesc{pA2x, pA2x + kBND, 2048, 0, 1};
      } else {
        gs.s[2] = SlotDesc{bAx,  nullptr, 2048, 0, 0};
        gs.s[4] = SlotDesc{bA2x, nullptr, 2048, 0, 0};
      }
      if (path == 2) {
        gs.s[3] = SlotDesc{bAh,  nullptr, 2048, 0, 0};
        gs.s[5] = SlotDesc{bA2h, nullptr, 2048, 0, 0};
      } else {
        gs.s[3] = SlotDesc{pAh,  pAh + kBND,  2048, 0, 1};
        gs.s[5] = SlotDesc{pA2h, pA2h + kBND, 2048, 0, 1};
      }
      k_gate<<<dim3(256, 1, 1), 256, 0, stream>>>(
          gs, WgT + (size_t)l * 128 * 384, bg + l * 128, h32, zh_bf, zhT, r32);

      // ---- phase 1 diffusion (zh) -> overwrites the "h" slabs ----
      if (path == 2)
        k_diff<<<dim3(32, 8, 1), 256, 0, stream>>>(
            A_bf, A2_bf, nullptr, 0, 0, 0, zhT,
            Out4f{}, Out4b{nullptr, bAh, nullptr, bA2h}, 2048, 1);
      else
        k_diff<<<dim3(32, 8, SK), 256, 0, stream>>>(
            A_bf, A2_bf, nullptr, 0, 0, 0, zhT,
            Out4f{nullptr, pAh, nullptr, pA2h}, Out4b{}, 2048 / SK, 0);

      // ---- candidate + GRU update ----
      Slots6 cs = gs;
      cs.s[1] = SlotDesc{zh_bf, nullptr, 2048, 0, 0};
      k_cand<<<dim3(256, 1, 1), 256, 0, stream>>>(
          cs, WuT + (size_t)l * 64 * 384, bu + l * 64, r32, h32, hT, h_bf,
          x, outCur, outHid + (size_t)l * kBND, t);
    }
  }
}

// Round 3
// 5224.067 us; speedup vs baseline: 1.7369x; 1.4171x over previous
//
#include <hip/hip_runtime.h>
#include <hip/hip_bf16.h>
#include <math.h>

typedef __bf16 bf16x8 __attribute__((ext_vector_type(8)));
typedef float f32x4 __attribute__((ext_vector_type(4)));
typedef __hip_bfloat16 bf16s;

constexpr int kB = 16, kT = 24, kN = 2048, kD = 64;
constexpr size_t kBND = (size_t)kB * kN * kD;  // 2097152

struct SlotDesc { const void* p; int astr; int trow; int isF32; };
struct Slots6 { SlotDesc s[6]; };
struct DiffGrp { const bf16s* src; bf16s* oA; bf16s* oA2; };
struct DiffP { const bf16s* S0; const bf16s* S1; DiffGrp g[4]; int colsPerGrp; };

__device__ __forceinline__ void async_copy16(void* lds, const void* g) {
  __builtin_amdgcn_global_load_lds((const __attribute__((address_space(1))) void*)g,
                                   (__attribute__((address_space(3))) void*)lds,
                                   16, 0, 0);
}

// LDS tiles are [rows][64] bf16 (128B rows), staged linearly by global_load_lds.
// XOR swizzle (involution on 16B chunks within a row): staged source chunk =
// (tid&7) ^ (row&7); read chunk = g ^ (row&7). After swizzle the 16 lanes of a
// ds_read_b128 group span 8 bank-quads (2-way = free) instead of 16-way.

// ---------------- diffusion core: C[128x128] = S[m0:,:2048] @ Bsrc[c0:,:2048]^T ----------------
__device__ __forceinline__ void diff_core(
    const bf16s* __restrict__ S, const bf16s* __restrict__ Bsrc,
    int m0, int c0, bf16s* lA, bf16s* lB, f32x4 (&acc)[4][4])
{
  const int tid = threadIdx.x, lane = tid & 63, wave = tid >> 6;
  const int wm = (wave >> 1) * 64, wn = (wave & 1) * 64;
  const f32x4 zero = {0.f, 0.f, 0.f, 0.f};
#pragma unroll
  for (int i = 0; i < 4; ++i)
#pragma unroll
    for (int j = 0; j < 4; ++j) acc[i][j] = zero;

  const int ra = tid >> 3;
  const int cs = ((tid & 7) ^ (ra & 7)) * 8;          // swizzled source chunk (elems)
  const int rk0 = (((lane >> 4)) ^ (lane & 7)) * 8;    // swizzled read chunk, ks=0
  const int rk1 = ((4 + (lane >> 4)) ^ (lane & 7)) * 8;

  for (int k0 = 0; k0 < 2048; k0 += 64) {
#pragma unroll
    for (int i = 0; i < 4; ++i)
      async_copy16(lA + (size_t)(i * 256 + tid) * 8,
                   S + (size_t)(m0 + i * 32 + ra) * 2048 + k0 + cs);
#pragma unroll
    for (int i = 0; i < 4; ++i)
      async_copy16(lB + (size_t)(i * 256 + tid) * 8,
                   Bsrc + (size_t)(c0 + i * 32 + ra) * 2048 + k0 + cs);
    __syncthreads();
#pragma unroll
    for (int ks = 0; ks < 2; ++ks) {
      const int rk = ks ? rk1 : rk0;
      bf16x8 av[4], bv[4];
#pragma unroll
      for (int f = 0; f < 4; ++f) {
        av[f] = *(const bf16x8*)(lA + (size_t)(wm + f * 16 + (lane & 15)) * 64 + rk);
        bv[f] = *(const bf16x8*)(lB + (size_t)(wn + f * 16 + (lane & 15)) * 64 + rk);
      }
#pragma unroll
      for (int i = 0; i < 4; ++i)
#pragma unroll
        for (int j = 0; j < 4; ++j)
          acc[i][j] = __builtin_amdgcn_mfma_f32_16x16x32_bf16(av[i], bv[j], acc[i][j], 0, 0, 0);
    }
    __syncthreads();
  }
}

// ---------------- diffusion kernel: up to 4 column groups, 2 supports ----------------
// out[group slab][(c2>>6)*2048 + n][c2&63] = S @ src, c2 group-local.
__global__ __launch_bounds__(256) void k_diff(DiffP p)
{
  __shared__ bf16s lA[128 * 64];
  __shared__ bf16s lB[128 * 64];
  const int mi = blockIdx.x;
  const bf16s* S = (mi >> 4) ? p.S1 : p.S0;
  const int m0 = (mi & 15) * 128;
  const int ybpg = p.colsPerGrp >> 7;
  const int grp = blockIdx.y / ybpg;
  const int c0 = (blockIdx.y - grp * ybpg) * 128;
  const DiffGrp G = p.g[grp];

  f32x4 acc[4][4];
  diff_core(S, G.src, m0, c0, lA, lB, acc);

  bf16s* out = (mi >> 4) ? G.oA2 : G.oA;
  const int lane = threadIdx.x & 63, wave = threadIdx.x >> 6;
  const int wm = (wave >> 1) * 64, wn = (wave & 1) * 64;
  const int rq = (lane >> 4) * 4, cl = lane & 15;
#pragma unroll
  for (int fm = 0; fm < 4; ++fm)
#pragma unroll
    for (int fn = 0; fn < 4; ++fn)
#pragma unroll
      for (int q = 0; q < 4; ++q) {
        int gm = m0 + wm + fm * 16 + rq + q;
        int gc = c0 + wn + fn * 16 + cl;
        size_t off = ((size_t)(gc >> 6) * 2048 + gm) * 64 + (gc & 63);
        out[off] = __float2bfloat16(acc[fm][fn][q]);
      }
}

// ---------------- setup: A2 = 2*A@A - I ----------------
__global__ __launch_bounds__(256) void k_a2(
    const bf16s* __restrict__ A, const bf16s* __restrict__ AT, bf16s* A2)
{
  __shared__ bf16s lA[128 * 64];
  __shared__ bf16s lB[128 * 64];
  const int m0 = blockIdx.x * 128, n0 = blockIdx.y * 128;
  f32x4 acc[4][4];
  diff_core(A, AT, m0, n0, lA, lB, acc);
  const int lane = threadIdx.x & 63, wave = threadIdx.x >> 6;
  const int wm = (wave >> 1) * 64, wn = (wave & 1) * 64;
  const int rq = (lane >> 4) * 4, cl = lane & 15;
#pragma unroll
  for (int fm = 0; fm < 4; ++fm)
#pragma unroll
    for (int fn = 0; fn < 4; ++fn)
#pragma unroll
      for (int q = 0; q < 4; ++q) {
        int gm = m0 + wm + fm * 16 + rq + q;
        int gc = n0 + wn + fn * 16 + cl;
        A2[(size_t)gm * 2048 + gc] = __float2bfloat16(2.f * acc[fm][fn][q] - (gm == gc ? 1.f : 0.f));
      }
}

// ---------------- small GEMM core (gate/cand): K = 6 slots of 64 ----------------
template<int BN>
__device__ __forceinline__ void small_core(
    const Slots6& sl, int m0, const bf16s* __restrict__ W,
    bf16s* lA, bf16s* lB, f32x4 (&acc)[4][BN / 32])
{
  const int tid = threadIdx.x, lane = tid & 63, wave = tid >> 6;
  const int wm = (wave >> 1) * 64, wn = (wave & 1) * (BN / 2);
  const f32x4 zero = {0.f, 0.f, 0.f, 0.f};
#pragma unroll
  for (int i = 0; i < 4; ++i)
#pragma unroll
    for (int j = 0; j < BN / 32; ++j) acc[i][j] = zero;

  const int ra = tid >> 3;
  const int cs = ((tid & 7) ^ (ra & 7)) * 8;
  const int rk0 = (((lane >> 4)) ^ (lane & 7)) * 8;
  const int rk1 = ((4 + (lane >> 4)) ^ (lane & 7)) * 8;

#pragma unroll
  for (int ks = 0; ks < 6; ++ks) {
    const SlotDesc sd = sl.s[ks];
    if (!sd.isF32) {
      const bf16s* base = (const bf16s*)sd.p;
#pragma unroll
      for (int i = 0; i < 4; ++i) {
        int row = m0 + i * 32 + ra;
        size_t roff = ((size_t)(row >> 11) * sd.astr + sd.trow + (row & 2047)) * 64 + cs;
        async_copy16(lA + (size_t)(i * 256 + tid) * 8, base + roff);
      }
    } else {
#pragma unroll
      for (int i = 0; i < 4; ++i) {
        int row = m0 + i * 32 + ra;
        size_t roff = ((size_t)(row >> 11) * sd.astr + sd.trow + (row & 2047)) * 64 + cs;
        const float4* q0 = (const float4*)((const float*)sd.p + roff);
        float4 a = q0[0], b = q0[1];
        union { bf16x8 v; bf16s h[8]; } u;
        u.h[0] = __float2bfloat16(a.x); u.h[1] = __float2bfloat16(a.y);
        u.h[2] = __float2bfloat16(a.z); u.h[3] = __float2bfloat16(a.w);
        u.h[4] = __float2bfloat16(b.x); u.h[5] = __float2bfloat16(b.y);
        u.h[6] = __float2bfloat16(b.z); u.h[7] = __float2bfloat16(b.w);
        *(bf16x8*)(lA + (size_t)(i * 256 + tid) * 8) = u.v;
      }
    }
#pragma unroll
    for (int i = 0; i < BN / 32; ++i)
      async_copy16(lB + (size_t)(i * 256 + tid) * 8,
                   W + (size_t)(i * 32 + ra) * 384 + ks * 64 + cs);
    __syncthreads();
#pragma unroll
    for (int kss = 0; kss < 2; ++kss) {
      const int rk = kss ? rk1 : rk0;
      bf16x8 av[4], bv[BN / 32];
#pragma unroll
      for (int f = 0; f < 4; ++f)
        av[f] = *(const bf16x8*)(lA + (size_t)(wm + f * 16 + (lane & 15)) * 64 + rk);
#pragma unroll
      for (int f = 0; f < BN / 32; ++f)
        bv[f] = *(const bf16x8*)(lB + (size_t)(wn + f * 16 + (lane & 15)) * 64 + rk);
#pragma unroll
      for (int i = 0; i < 4; ++i)
#pragma unroll
        for (int j = 0; j < BN / 32; ++j)
          acc[i][j] = __builtin_amdgcn_mfma_f32_16x16x32_bf16(av[i], bv[j], acc[i][j], 0, 0, 0);
    }
    __syncthreads();
  }
}

// ---------------- gate (two layers in one launch) ----------------
struct LayerG {
  Slots6 sl; const bf16s* W; const float* bias;
  const float* h; bf16s* zh; bf16s* zhT; float* r;
};
__global__ __launch_bounds__(256) void k_gate(LayerG A, LayerG B, int nA)
{
  __shared__ bf16s lA[128 * 64];
  __shared__ bf16s lB[128 * 64];
  const int bx = blockIdx.x;
  const bool isA = bx < nA;
  const LayerG L = isA ? A : B;
  const int m0 = (isA ? bx : bx - nA) * 128;
  f32x4 acc[4][4];
  small_core<128>(L.sl, m0, L.W, lA, lB, acc);
  const int lane = threadIdx.x & 63, wave = threadIdx.x >> 6;
  const int wm = (wave >> 1) * 64, wn = (wave & 1) * 64;
  const int rq = (lane >> 4) * 4, cl = lane & 15;
#pragma unroll
  for (int fm = 0; fm < 4; ++fm)
#pragma unroll
    for (int fn = 0; fn < 4; ++fn) {
      const int o = wn + fn * 16 + cl;
      const float bias = L.bias[o];
#pragma unroll
      for (int q = 0; q < 4; ++q) {
        size_t gm = (size_t)m0 + wm + fm * 16 + rq + q;
        float s = 1.f / (1.f + expf(-(acc[fm][fn][q] + bias)));
        if (o < 64) {
          float zh = s * L.h[gm * 64 + o];
          L.zh[gm * 64 + o] = __float2bfloat16(zh);
          L.zhT[((size_t)((gm >> 11) * 64 + o)) * 2048 + (gm & 2047)] = __float2bfloat16(zh);
        } else {
          L.r[gm * 64 + (o - 64)] = s;
        }
      }
    }
}

// ---------------- candidate + GRU update (two layers in one launch) ----------------
struct LayerC {
  Slots6 sl; const bf16s* W; const float* bias;
  const float* r; float* h32; bf16s* hT; bf16s* h_bf; float* hid;
  bf16s* x1; bf16s* x1T;     // layer-0: write x1 = x + h (null for layer-1)
  float* outC;               // layer-1: write outCur (null for layer-0)
  const float* x0; int t;
};
__global__ __launch_bounds__(256) void k_cand(LayerC A, LayerC B, int nA)
{
  __shared__ bf16s lA[128 * 64];
  __shared__ bf16s lB[64 * 64];
  const int bx = blockIdx.x;
  const bool isA = bx < nA;
  const LayerC L = isA ? A : B;
  const int m0 = (isA ? bx : bx - nA) * 128;
  f32x4 acc[4][2];
  small_core<64>(L.sl, m0, L.W, lA, lB, acc);
  const int lane = threadIdx.x & 63, wave = threadIdx.x >> 6;
  const int wm = (wave >> 1) * 64, wn = (wave & 1) * 32;
  const int rq = (lane >> 4) * 4, cl = lane & 15;
#pragma unroll
  for (int fm = 0; fm < 4; ++fm)
#pragma unroll
    for (int fn = 0; fn < 2; ++fn) {
      const int d = wn + fn * 16 + cl;
      const float bias = L.bias[d];
#pragma unroll
      for (int q = 0; q < 4; ++q) {
        size_t gm = (size_t)m0 + wm + fm * 16 + rq + q;
        float hc = tanhf(acc[fm][fn][q] + bias);
        float r = L.r[gm * 64 + d];
        float h = L.h32[gm * 64 + d];
        float hn = r * h + (1.f - r) * hc;
        L.h32[gm * 64 + d] = hn;
        int b = (int)(gm >> 11), n = (int)(gm & 2047);
        L.hT[((size_t)(b * 64 + d)) * 2048 + n] = __float2bfloat16(hn);
        L.h_bf[gm * 64 + d] = __float2bfloat16(hn);
        size_t xi = (((size_t)b * kT + L.t) * 2048 + n) * 64 + d;
        if (L.x1) {
          float xv = L.x0[xi] + hn;
          L.x1[gm * 64 + d] = __float2bfloat16(xv);
          L.x1T[((size_t)(b * 64 + d)) * 2048 + n] = __float2bfloat16(xv);
        }
        if (L.outC) L.outC[xi] = L.x0[xi] + hn;
        if (L.hid) L.hid[gm * 64 + d] = hn;
      }
    }
}

// ---------------- utility kernels ----------------
__global__ __launch_bounds__(256) void transpose_cvt(
    const float* in, bf16s* out, int nrows, int ncols,
    size_t in_ostride, size_t out_ostride)
{
  __shared__ float tile[64][65];
  const int r0 = blockIdx.x * 64, c0 = blockIdx.y * 64;
  in  += (size_t)blockIdx.z * in_ostride;
  out += (size_t)blockIdx.z * out_ostride;
  const int tx = threadIdx.x & 63, ty = threadIdx.x >> 6;
#pragma unroll
  for (int i = 0; i < 64; i += 4)
    tile[ty + i][tx] = in[(size_t)(r0 + ty + i) * ncols + c0 + tx];
  __syncthreads();
#pragma unroll
  for (int i = 0; i < 64; i += 4)
    out[(size_t)(c0 + ty + i) * nrows + r0 + tx] = __float2bfloat16(tile[tx][ty + i]);
}

__global__ __launch_bounds__(256) void k_cvt(const float* in, bf16s* out, int n)
{
  int i = blockIdx.x * 256 + threadIdx.x;
  if (i < n) out[i] = __float2bfloat16(in[i]);
}

__global__ __launch_bounds__(256) void k_repack(
    const float* Wg, const float* Wu, bf16s* WgT, bf16s* WuT)
{
  int idx = blockIdx.x * 256 + threadIdx.x;
  if (idx < 2 * 3 * 128 * 128) {
    int o = idx & 127, cin = (idx >> 7) & 127, k = (idx >> 14) % 3, l = idx / 49152;
    WgT[((size_t)(l * 128 + o)) * 384 + (2 * k + (cin >> 6)) * 64 + (cin & 63)] =
        __float2bfloat16(Wg[idx]);
  }
  if (idx < 2 * 3 * 128 * 64) {
    int o = idx & 63, cin = (idx >> 6) & 127, k = (idx >> 13) % 3, l = idx / 24576;
    WuT[((size_t)(l * 64 + o)) * 384 + (2 * k + (cin >> 6)) * 64 + (cin & 63)] =
        __float2bfloat16(Wu[idx]);
  }
}

__global__ __launch_bounds__(256) void init_layer(
    const float* ist_l, float* h32, bf16s* hT, bf16s* h_bf)
{
  size_t idx = (size_t)blockIdx.x * 256 + threadIdx.x;
  if (idx >= kBND) return;
  int d = (int)(idx & 63);
  size_t row = idx >> 6;
  int n = (int)(row & 2047), b = (int)(row >> 11);
  float h = ist_l[idx];
  h32[idx] = h;
  hT[((size_t)(b * 64 + d)) * 2048 + n] = __float2bfloat16(h);
  h_bf[idx] = __float2bfloat16(h);
}

// ---------------- host orchestration ----------------
extern "C" void kernel_launch(void* const* d_in, const int* in_sizes, int n_in,
                              void* d_out, int out_size, void* d_ws, size_t ws_size,
                              hipStream_t stream)
{
  (void)in_sizes; (void)n_in; (void)out_size;
  const float* x   = (const float*)d_in[0];
  const float* ist = (const float*)d_in[1];
  const float* adj = (const float*)d_in[2];
  const float* Wg  = (const float*)d_in[3];
  const float* bg  = (const float*)d_in[4];
  const float* Wu  = (const float*)d_in[5];
  const float* bu  = (const float*)d_in[6];
  float* outCur = (float*)d_out;
  float* outHid = outCur + (size_t)kB * kT * kN * kD;

  char* p = (char*)d_ws;
  auto carve = [&](size_t bytes) { char* q = p; p += (bytes + 255) & ~(size_t)255; return q; };
  bf16s* A_bf  = (bf16s*)carve((size_t)2048 * 2048 * 2);
  bf16s* A2_bf = (bf16s*)carve((size_t)2048 * 2048 * 2);
  bf16s* WgT   = (bf16s*)carve((size_t)2 * 128 * 384 * 2);
  bf16s* WuT   = (bf16s*)carve((size_t)2 * 64 * 384 * 2);
  float* h32b  = (float*)carve(2 * kBND * 4);
  float* r32b  = (float*)carve(2 * kBND * 4);
  bf16s* hTb   = (bf16s*)carve(2 * kBND * 2);
  bf16s* hbfb  = (bf16s*)carve(2 * kBND * 2);
  bf16s* zhTb  = (bf16s*)carve(2 * kBND * 2);
  bf16s* zhbfb = (bf16s*)carve(2 * kBND * 2);
  bf16s* x1_bf = (bf16s*)carve(kBND * 2);
  bf16s* x1T   = (bf16s*)carve(kBND * 2);
  bf16s* sAh0  = (bf16s*)carve(kBND * 2);
  bf16s* sA2h0 = (bf16s*)carve(kBND * 2);
  bf16s* sAh1  = (bf16s*)carve(kBND * 2);
  bf16s* sA2h1 = (bf16s*)carve(kBND * 2);
  bf16s* sAx1  = (bf16s*)carve(kBND * 2);
  bf16s* sA2x1 = (bf16s*)carve(kBND * 2);

  float* h32_0 = h32b;            float* h32_1 = h32b + kBND;
  float* r32_0 = r32b;            float* r32_1 = r32b + kBND;
  bf16s* hT0 = hTb;               bf16s* hT1 = hTb + kBND;
  bf16s* hbf0 = hbfb;             bf16s* hbf1 = hbfb + kBND;
  bf16s* zhT0 = zhTb;             bf16s* zhT1 = zhTb + kBND;
  bf16s* zhbf0 = zhbfb;           bf16s* zhbf1 = zhbfb + kBND;

  size_t used = (size_t)(p - (char*)d_ws);
  size_t rem = (ws_size > used) ? ws_size - used : 0;
  const size_t xTfull = (size_t)kB * kT * kD * kN * 2;   // 96 MiB
  bool batched0 = rem >= (xTfull / 2 + 2 * xTfull + (1 << 20));

  bf16s *AT_bf, *AxF = nullptr, *A2xF = nullptr, *xTh = nullptr;
  bf16s *x0T = nullptr, *sAx0 = nullptr, *sA2x0 = nullptr;
  if (batched0) {
    AxF  = (bf16s*)carve(xTfull);
    A2xF = (bf16s*)carve(xTfull);
    xTh  = (bf16s*)carve(xTfull / 2);
    AT_bf = AxF;  // alias: AT dead (after k_a2) before AxF is written
  } else {
    AT_bf = (bf16s*)carve((size_t)2048 * 2048 * 2);
    x0T   = (bf16s*)carve(kBND * 2);
    sAx0  = (bf16s*)carve(kBND * 2);
    sA2x0 = (bf16s*)carve(kBND * 2);
  }

  // ---- setup ----
  k_cvt<<<dim3((2048 * 2048 + 255) / 256), 256, 0, stream>>>(adj, A_bf, 2048 * 2048);
  transpose_cvt<<<dim3(32, 32, 1), 256, 0, stream>>>(adj, AT_bf, 2048, 2048, 0, 0);
  k_a2<<<dim3(16, 16, 1), 256, 0, stream>>>(A_bf, AT_bf, A2_bf);
  k_repack<<<dim3(384), 256, 0, stream>>>(Wg, Wu, WgT, WuT);
  init_layer<<<dim3((int)(kBND / 256)), 256, 0, stream>>>(ist, h32_0, hT0, hbf0);
  init_layer<<<dim3((int)(kBND / 256)), 256, 0, stream>>>(ist + kBND, h32_1, hT1, hbf1);

  // ---- batched layer-0 x-diffusion (two halves to bound ws) ----
  if (batched0) {
    for (int h = 0; h < 2; ++h) {
      size_t off = (size_t)h * 8 * kT * 131072;
      transpose_cvt<<<dim3(32, 1, 8 * kT), 256, 0, stream>>>(x + off, xTh, 2048, 64, 131072, 131072);
      DiffP dp; dp.S0 = A_bf; dp.S1 = A2_bf; dp.colsPerGrp = 12288;
      dp.g[0] = DiffGrp{xTh, AxF + off, A2xF + off};
      dp.g[1] = dp.g[2] = dp.g[3] = DiffGrp{nullptr, nullptr, nullptr};
      k_diff<<<dim3(32, 96), 256, 0, stream>>>(dp);
    }
  }

  // ---- pipelined supersteps: s runs cell(0,s) and cell(1,s-1) ----
  for (int s = 0; s <= kT; ++s) {
    const bool aA = (s < kT), aB = (s >= 1);
    const int tA = s, tB = s - 1;
    const int nA = aA ? 256 : 0, nB = aB ? 256 : 0;

    if (aA && !batched0)
      transpose_cvt<<<dim3(32, 1, kB), 256, 0, stream>>>(
          x + (size_t)tA * 131072, x0T, 2048, 64, (size_t)kT * 131072, 131072);

    // phase-0 diffusion: h0 | (x0) | h1, x1
    {
      DiffP dp; dp.S0 = A_bf; dp.S1 = A2_bf; dp.colsPerGrp = 1024;
      int ng = 0;
      if (aA)              dp.g[ng++] = DiffGrp{hT0, sAh0, sA2h0};
      if (aA && !batched0) dp.g[ng++] = DiffGrp{x0T, sAx0, sA2x0};
      if (aB) { dp.g[ng++] = DiffGrp{hT1, sAh1, sA2h1};
                dp.g[ng++] = DiffGrp{x1T, sAx1, sA2x1}; }
      for (int i = ng; i < 4; ++i) dp.g[i] = DiffGrp{nullptr, nullptr, nullptr};
      k_diff<<<dim3(32, 8 * ng), 256, 0, stream>>>(dp);
    }

    // gate
    {
      LayerG GA = {}, GB = {};
      if (aA) {
        GA.sl.s[0] = SlotDesc{x, kT * 2048, tA * 2048, 1};
        GA.sl.s[1] = SlotDesc{hbf0, 2048, 0, 0};
        GA.sl.s[2] = batched0 ? SlotDesc{AxF,  kT * 2048, tA * 2048, 0} : SlotDesc{sAx0, 2048, 0, 0};
        GA.sl.s[3] = SlotDesc{sAh0, 2048, 0, 0};
        GA.sl.s[4] = batched0 ? SlotDesc{A2xF, kT * 2048, tA * 2048, 0} : SlotDesc{sA2x0, 2048, 0, 0};
        GA.sl.s[5] = SlotDesc{sA2h0, 2048, 0, 0};
        GA.W = WgT; GA.bias = bg; GA.h = h32_0; GA.zh = zhbf0; GA.zhT = zhT0; GA.r = r32_0;
      }
      if (aB) {
        GB.sl.s[0] = SlotDesc{x1_bf, 2048, 0, 0};
        GB.sl.s[1] = SlotDesc{hbf1, 2048, 0, 0};
        GB.sl.s[2] = SlotDesc{sAx1, 2048, 0, 0};
        GB.sl.s[3] = SlotDesc{sAh1, 2048, 0, 0};
        GB.sl.s[4] = SlotDesc{sA2x1, 2048, 0, 0};
        GB.sl.s[5] = SlotDesc{sA2h1, 2048, 0, 0};
        GB.W = WgT + (size_t)128 * 384; GB.bias = bg + 128;
        GB.h = h32_1; GB.zh = zhbf1; GB.zhT = zhT1; GB.r = r32_1;
      }
      k_gate<<<dim3(nA + nB), 256, 0, stream>>>(GA, GB, nA);
    }

    // phase-1 diffusion: zh0 | zh1 (overwrite h-slabs)
    {
      DiffP dp; dp.S0 = A_bf; dp.S1 = A2_bf; dp.colsPerGrp = 1024;
      int ng = 0;
      if (aA) dp.g[ng++] = DiffGrp{zhT0, sAh0, sA2h0};
      if (aB) dp.g[ng++] = DiffGrp{zhT1, sAh1, sA2h1};
      for (int i = ng; i < 4; ++i) dp.g[i] = DiffGrp{nullptr, nullptr, nullptr};
      k_diff<<<dim3(32, 8 * ng), 256, 0, stream>>>(dp);
    }

    // candidate + GRU update
    {
      LayerC CA = {}, CB = {};
      if (aA) {
        CA.sl = LayerG{}.sl;  // zero then fill
        CA.sl.s[0] = SlotDesc{x, kT * 2048, tA * 2048, 1};
        CA.sl.s[1] = SlotDesc{zhbf0, 2048, 0, 0};
        CA.sl.s[2] = batched0 ? SlotDesc{AxF,  kT * 2048, tA * 2048, 0} : SlotDesc{sAx0, 2048, 0, 0};
        CA.sl.s[3] = SlotDesc{sAh0, 2048, 0, 0};
        CA.sl.s[4] = batched0 ? SlotDesc{A2xF, kT * 2048, tA * 2048, 0} : SlotDesc{sA2x0, 2048, 0, 0};
        CA.sl.s[5] = SlotDesc{sA2h0, 2048, 0, 0};
        CA.W = WuT; CA.bias = bu; CA.r = r32_0; CA.h32 = h32_0; CA.hT = hT0; CA.h_bf = hbf0;
        CA.hid = (tA == kT - 1) ? outHid : nullptr;
        CA.x1 = x1_bf; CA.x1T = x1T; CA.outC = nullptr; CA.x0 = x; CA.t = tA;
      }
      if (aB) {
        CB.sl.s[0] = SlotDesc{x1_bf, 2048, 0, 0};
        CB.sl.s[1] = SlotDesc{zhbf1, 2048, 0, 0};
        CB.sl.s[2] = SlotDesc{sAx1, 2048, 0, 0};
        CB.sl.s[3] = SlotDesc{sAh1, 2048, 0, 0};
        CB.sl.s[4] = SlotDesc{sA2x1, 2048, 0, 0};
        CB.sl.s[5] = SlotDesc{sA2h1, 2048, 0, 0};
        CB.W = WuT + (size_t)64 * 384; CB.bias = bu + 64;
        CB.r = r32_1; CB.h32 = h32_1; CB.hT = hT1; CB.h_bf = hbf1;
        CB.hid = (tB == kT - 1) ? outHid + kBND : nullptr;
        CB.x1 = nullptr; CB.x1T = nullptr; CB.outC = outCur; CB.x0 = x; CB.t = tB;
      }
      k_cand<<<dim3(nA + nB), 256, 0, stream>>>(CA, CB, nA);
    }
  }
}